// Round 7
// baseline (1216.594 us; speedup 1.0000x reference)
//
#include <hip/hip_runtime.h>
#include <hip/hip_bf16.h>
#include <stdint.h>

// Problem constants (reference: N=4096, D=1024, V=50257)
#define NROWS 4096
#define DDIM  1024
#define VDIM  50257
#define VPAD  50432   // 197 * 256 (v padded to 256-wide block tiles)
#define NVT   197     // v-tiles (256 wide)
#define NMT   16      // m-tiles (256 rows each)

// fp8 scales: w*64, x*8 -> logits scaled by 512 (exact pow2, descale pre-exp)
#define DESCALE (1.0f / 512.0f)

typedef int   i32x4 __attribute__((ext_vector_type(4)));
typedef int   i32x8 __attribute__((ext_vector_type(8)));
typedef float f32x16 __attribute__((ext_vector_type(16)));

// e8m0 1.0 scales (exponent 127 -> 2^0): numerically exact, keeps absmax 0.
#define SCALE1 0x7F7F7F7F

// Fragment-ordered quantized layout (pre-swizzled in cvtq_frag):
//   frag (g, c) = 2 KB at byte ((g*16 + c)*64 + l)*32 + b,
//   holding src[g*32 + (l&31)][c*64 + (l>>5)*32 + b],  b = 0..31.
// This is exactly the 32x32x64 scaled-MFMA operand mapping (HW-verified
// rounds 1-6, absmax 0.0). A wave's fragment load is two fully coalesced
// global_load_dwordx4 (2 KB burst) -> no LDS, no barriers.
__device__ __forceinline__ i32x8 ld_gfrag(const uint8_t* p) {
  i32x4 lo = *(const i32x4*)p;
  i32x4 hi = *(const i32x4*)(p + 16);
  return __builtin_shufflevector(lo, hi, 0, 1, 2, 3, 4, 5, 6, 7);
}

// ---- fp32 -> fp8 e4m3, written in fragment order; zero pad rows ----
__global__ __launch_bounds__(256)
void cvtq_frag_kernel(const float* __restrict__ src, uint32_t* __restrict__ dst,
                      int nrows_valid, float scale) {
  int t = blockIdx.x * 256 + threadIdx.x;
  int l  = t & 63;
  int gc = t >> 6;                    // g*16 + c
  int row = (gc >> 4) * 32 + (l & 31);
  int col = (gc & 15) * 64 + (l >> 5) * 32;
  uint32_t o[8] = {0u,0u,0u,0u,0u,0u,0u,0u};
  if (row < nrows_valid) {
    const float4* s = (const float4*)(src + (size_t)row * DDIM + col);
    #pragma unroll
    for (int d = 0; d < 8; ++d) {
      float4 f = s[d];
      uint32_t v = 0;
      v = __builtin_amdgcn_cvt_pk_fp8_f32(f.x * scale, f.y * scale, v, false);
      v = __builtin_amdgcn_cvt_pk_fp8_f32(f.z * scale, f.w * scale, v, true);
      o[d] = v;
    }
  }
  uint4* dp = (uint4*)(dst + (size_t)t * 8);
  dp[0] = make_uint4(o[0], o[1], o[2], o[3]);
  dp[1] = make_uint4(o[4], o[5], o[6], o[7]);
}

// ---- exact fp32 target logit: lt[n] = dot(x[n], w[target[n]]) ----
__global__ __launch_bounds__(256)
void tlogit_kernel(const float* __restrict__ x, const float* __restrict__ w,
                   const int* __restrict__ tgt, float* __restrict__ lt) {
  int n = blockIdx.x;
  int t = tgt[n];
  const float4* xr = (const float4*)(x + (size_t)n * DDIM);
  const float4* wr = (const float4*)(w + (size_t)t * DDIM);
  float4 a = xr[threadIdx.x];
  float4 b = wr[threadIdx.x];
  float s = a.x * b.x + a.y * b.y + a.z * b.z + a.w * b.w;
  #pragma unroll
  for (int m = 32; m; m >>= 1) s += __shfl_down(s, m);
  __shared__ float red[4];
  if ((threadIdx.x & 63) == 0) red[threadIdx.x >> 6] = s;
  __syncthreads();
  if (threadIdx.x == 0) lt[n] = red[0] + red[1] + red[2] + red[3];
}

// ---- fused fp8 GEMM (scaled 32x32x64 f8f6f4, unit scales) + exp + row-sum ----
// LDS-FREE, 1 wave/SIMD, 128x128 wave tile. Block 256m x 256v, 4 waves
// (2m x 2n). Per k-iter: 8 frag loads (4A+4B, 16 KB) -> 16 scaled MFMAs
// (2.0 MFMA per frag-load; rounds 4/6's 128x64 tile at 1.33 was L2-return
// bandwidth-bound: 96 KB/CU-pair-iter vs ~60 B/cyc/CU). Now VMEM (~1090
// cyc/CU-iter) and MFMA (~1104 cyc/SIMD-iter) are balanced. launch_bounds
// (256,1): full 512-reg budget/wave -> acc 256 + frags 128 + addr fits
// (round 5's spill was the 2-waves/SIMD 256-reg cap). Loads issue first,
// sched_barrier, then the 1104-cyc MFMA cluster hides next-iter latency.
// XCD swizzle: the 16 m-tiles of one v-slab share flat&7 -> one XCD streams
// each weight slab once; fragment A (4MB) L2-resident per XCD.
__global__ __launch_bounds__(256, 1)
void gemm_lse_kernel(const uint8_t* __restrict__ xqf,  // frag-ordered fp8 x
                     const uint8_t* __restrict__ wqf,  // frag-ordered fp8 w
                     float* __restrict__ S) {          // [NROWS] sum of exp
  const int tid  = threadIdx.x;
  const int wid  = tid >> 6;    // 0..3
  const int lane = tid & 63;
  const int c31  = lane & 31;
  const int h    = lane >> 5;   // 0..1

  // Block remap: grid (16,197) -> flat. Full chunks of 128 flat ids cover 8
  // v-tiles x 16 m with same-v blocks sharing flat&7 (same XCD under id%8
  // round-robin). Tail 80 blocks (v-tiles 192..196) mapped bijectively.
  const int flat = blockIdx.x + blockIdx.y * 16;
  int bm, vt;
  if (flat >= 24 * 128) { int r = flat - 24 * 128; bm = r / 5; vt = 192 + (r - bm * 5); }
  else { vt = (flat >> 7) * 8 + (flat & 7); bm = (flat >> 3) & 15; }
  const int m0 = bm * 256;
  const int v0 = vt * 256;

  const int wave_m = wid >> 1;  // 0..1
  const int wave_n = wid & 1;   // 0..1

  // Fragment base pointers: frag (g, c) at (g*16 + c)*2048 + lane*32.
  const uint8_t* pA0 = xqf + ((size_t)(bm * 8 + wave_m * 4 + 0) * 16) * 2048 + lane * 32;
  const uint8_t* pA1 = xqf + ((size_t)(bm * 8 + wave_m * 4 + 1) * 16) * 2048 + lane * 32;
  const uint8_t* pA2 = xqf + ((size_t)(bm * 8 + wave_m * 4 + 2) * 16) * 2048 + lane * 32;
  const uint8_t* pA3 = xqf + ((size_t)(bm * 8 + wave_m * 4 + 3) * 16) * 2048 + lane * 32;
  const uint8_t* pB0 = wqf + ((size_t)(vt * 8 + wave_n * 4 + 0) * 16) * 2048 + lane * 32;
  const uint8_t* pB1 = wqf + ((size_t)(vt * 8 + wave_n * 4 + 1) * 16) * 2048 + lane * 32;
  const uint8_t* pB2 = wqf + ((size_t)(vt * 8 + wave_n * 4 + 2) * 16) * 2048 + lane * 32;
  const uint8_t* pB3 = wqf + ((size_t)(vt * 8 + wave_n * 4 + 3) * 16) * 2048 + lane * 32;

  f32x16 acc00 = {}, acc01 = {}, acc02 = {}, acc03 = {};
  f32x16 acc10 = {}, acc11 = {}, acc12 = {}, acc13 = {};
  f32x16 acc20 = {}, acc21 = {}, acc22 = {}, acc23 = {};
  f32x16 acc30 = {}, acc31 = {}, acc32 = {}, acc33 = {};

  // Prologue: load iter-0 fragments.
  i32x8 af0 = ld_gfrag(pA0), af1 = ld_gfrag(pA1);
  i32x8 af2 = ld_gfrag(pA2), af3 = ld_gfrag(pA3);
  i32x8 bf0 = ld_gfrag(pB0), bf1 = ld_gfrag(pB1);
  i32x8 bf2 = ld_gfrag(pB2), bf3 = ld_gfrag(pB3);

  #pragma unroll 1   // named regs + manual distance-1 pipeline
  for (int c = 0; c < 16; ++c) {
    const size_t co2 = (size_t)((c + 1) & 15) * 2048;  // wrap: harmless re-hit

    // Issue next-iter loads (consumed after the full 16-MFMA cluster).
    i32x8 na0 = ld_gfrag(pA0 + co2), na1 = ld_gfrag(pA1 + co2);
    i32x8 na2 = ld_gfrag(pA2 + co2), na3 = ld_gfrag(pA3 + co2);
    i32x8 nb0 = ld_gfrag(pB0 + co2), nb1 = ld_gfrag(pB1 + co2);
    i32x8 nb2 = ld_gfrag(pB2 + co2), nb3 = ld_gfrag(pB3 + co2);

    __builtin_amdgcn_sched_barrier(0);  // loads issue above the MFMA cluster

    acc00 = __builtin_amdgcn_mfma_scale_f32_32x32x64_f8f6f4(af0, bf0, acc00, 0, 0, 0, SCALE1, 0, SCALE1);
    acc01 = __builtin_amdgcn_mfma_scale_f32_32x32x64_f8f6f4(af0, bf1, acc01, 0, 0, 0, SCALE1, 0, SCALE1);
    acc02 = __builtin_amdgcn_mfma_scale_f32_32x32x64_f8f6f4(af0, bf2, acc02, 0, 0, 0, SCALE1, 0, SCALE1);
    acc03 = __builtin_amdgcn_mfma_scale_f32_32x32x64_f8f6f4(af0, bf3, acc03, 0, 0, 0, SCALE1, 0, SCALE1);
    acc10 = __builtin_amdgcn_mfma_scale_f32_32x32x64_f8f6f4(af1, bf0, acc10, 0, 0, 0, SCALE1, 0, SCALE1);
    acc11 = __builtin_amdgcn_mfma_scale_f32_32x32x64_f8f6f4(af1, bf1, acc11, 0, 0, 0, SCALE1, 0, SCALE1);
    acc12 = __builtin_amdgcn_mfma_scale_f32_32x32x64_f8f6f4(af1, bf2, acc12, 0, 0, 0, SCALE1, 0, SCALE1);
    acc13 = __builtin_amdgcn_mfma_scale_f32_32x32x64_f8f6f4(af1, bf3, acc13, 0, 0, 0, SCALE1, 0, SCALE1);
    acc20 = __builtin_amdgcn_mfma_scale_f32_32x32x64_f8f6f4(af2, bf0, acc20, 0, 0, 0, SCALE1, 0, SCALE1);
    acc21 = __builtin_amdgcn_mfma_scale_f32_32x32x64_f8f6f4(af2, bf1, acc21, 0, 0, 0, SCALE1, 0, SCALE1);
    acc22 = __builtin_amdgcn_mfma_scale_f32_32x32x64_f8f6f4(af2, bf2, acc22, 0, 0, 0, SCALE1, 0, SCALE1);
    acc23 = __builtin_amdgcn_mfma_scale_f32_32x32x64_f8f6f4(af2, bf3, acc23, 0, 0, 0, SCALE1, 0, SCALE1);
    acc30 = __builtin_amdgcn_mfma_scale_f32_32x32x64_f8f6f4(af3, bf0, acc30, 0, 0, 0, SCALE1, 0, SCALE1);
    acc31 = __builtin_amdgcn_mfma_scale_f32_32x32x64_f8f6f4(af3, bf1, acc31, 0, 0, 0, SCALE1, 0, SCALE1);
    acc32 = __builtin_amdgcn_mfma_scale_f32_32x32x64_f8f6f4(af3, bf2, acc32, 0, 0, 0, SCALE1, 0, SCALE1);
    acc33 = __builtin_amdgcn_mfma_scale_f32_32x32x64_f8f6f4(af3, bf3, acc33, 0, 0, 0, SCALE1, 0, SCALE1);

    // Rotate prefetch registers into place.
    af0 = na0; af1 = na1; af2 = na2; af3 = na3;
    bf0 = nb0; bf1 = nb1; bf2 = nb2; bf3 = nb3;
  }

  // Epilogue: descale, exp, row-sum. 32x32 C/D: col = lane&31,
  // row = (reg&3) + 8*(reg>>2) + 4*(lane>>5).
  const f32x16* accp[4][4] = {{&acc00, &acc01, &acc02, &acc03},
                              {&acc10, &acc11, &acc12, &acc13},
                              {&acc20, &acc21, &acc22, &acc23},
                              {&acc30, &acc31, &acc32, &acc33}};
  #pragma unroll
  for (int mi = 0; mi < 4; ++mi) {
    #pragma unroll
    for (int r = 0; r < 16; ++r) {
      float pacc = 0.f;
      #pragma unroll
      for (int ni = 0; ni < 4; ++ni) {
        int v = v0 + wave_n * 128 + ni * 32 + c31;
        float e = __expf((*accp[mi][ni])[r] * DESCALE);
        pacc += (v < VDIM) ? e : 0.f;   // mask vocab pad
      }
      pacc += __shfl_xor(pacc, 16);
      pacc += __shfl_xor(pacc, 8);
      pacc += __shfl_xor(pacc, 4);
      pacc += __shfl_xor(pacc, 2);
      pacc += __shfl_xor(pacc, 1);
      if (c31 == 0) {
        int row = m0 + wave_m * 128 + mi * 32 + (r & 3) + 8 * (r >> 2) + 4 * h;
        atomicAdd(&S[row], pacc);
      }
    }
  }
}

// ---- final: loss = mean(log(S[n]) - lt[n]) ----
__global__ __launch_bounds__(1024)
void loss_kernel(const float* __restrict__ S, const float* __restrict__ lt,
                 float* __restrict__ out) {
  float s = 0.f;
  for (int n = threadIdx.x; n < NROWS; n += 1024)
    s += logf(S[n]) - lt[n];
  #pragma unroll
  for (int m = 32; m; m >>= 1) s += __shfl_down(s, m);
  __shared__ float red[16];
  if ((threadIdx.x & 63) == 0) red[threadIdx.x >> 6] = s;
  __syncthreads();
  if (threadIdx.x == 0) {
    float t = 0.f;
    #pragma unroll
    for (int i = 0; i < 16; ++i) t += red[i];
    out[0] = t / (float)NROWS;
  }
}

extern "C" void kernel_launch(void* const* d_in, const int* in_sizes, int n_in,
                              void* d_out, int out_size, void* d_ws, size_t ws_size,
                              hipStream_t stream) {
  const float* x = (const float*)d_in[0];   // [4096,1024] fp32
  const float* w = (const float*)d_in[1];   // [50257,1024] fp32
  const int*   t = (const int*)d_in[2];     // [4096] int
  float* out = (float*)d_out;

  char* ws = (char*)d_ws;
  const size_t wq_bytes = (size_t)VPAD * DDIM;    // 51.6 MB fp8 (frag order)
  const size_t xq_bytes = (size_t)NROWS * DDIM;   //  4.2 MB fp8 (frag order)
  uint8_t* wqf = (uint8_t*)ws;
  uint8_t* xqf = (uint8_t*)(ws + wq_bytes);
  float*   S   = (float*)(ws + wq_bytes + xq_bytes);
  float*   lt  = S + NROWS;

  if (ws_size < wq_bytes + xq_bytes + 2 * NROWS * sizeof(float)) return;

  hipMemsetAsync(S, 0, NROWS * sizeof(float), stream);
  // threads = rows*32 (one per (g,c,lane)); grid = rows*32/256 = rows/8
  cvtq_frag_kernel<<<VPAD / 8, 256, 0, stream>>>(w, (uint32_t*)wqf,
                                                 VDIM, 64.0f);
  cvtq_frag_kernel<<<NROWS / 8, 256, 0, stream>>>(x, (uint32_t*)xqf,
                                                  NROWS, 8.0f);
  tlogit_kernel<<<NROWS, 256, 0, stream>>>(x, w, t, lt);

  dim3 grid(NMT, NVT);  // (16, 197)
  gemm_lse_kernel<<<grid, 256, 0, stream>>>(xqf, wqf, S);

  loss_kernel<<<1, 1024, 0, stream>>>(S, lt, out);
}

// Round 8
// 666.379 us; speedup vs baseline: 1.8257x; 1.8257x over previous
//
#include <hip/hip_runtime.h>
#include <hip/hip_bf16.h>
#include <stdint.h>

// Problem constants (reference: N=4096, D=1024, V=50257)
#define NROWS 4096
#define DDIM  1024
#define VDIM  50257
#define VPAD  50304   // 393 * 128 = 1572 * 32
#define NVT   393     // v-tiles (128 wide)
#define NMT   16      // m-tiles (256 rows each)

// fp8 scales: w*64, x*8 -> logits scaled by 512 (exact pow2, descale pre-exp)
#define DESCALE (1.0f / 512.0f)

typedef int   i32x4 __attribute__((ext_vector_type(4)));
typedef int   i32x8 __attribute__((ext_vector_type(8)));
typedef float f32x16 __attribute__((ext_vector_type(16)));

// e8m0 1.0 scales (exponent 127 -> 2^0): numerically exact, keeps absmax 0.
#define SCALE1 0x7F7F7F7F

// Fragment-ordered quantized layout:
//   frag (g, c) = 2 KB at byte (g*16 + c)*2048 + l*32 + b,
//   holding src[g*32 + (l&31)][c*64 + (l>>5)*32 + b],  b = 0..31.
// This is exactly the 32x32x64 scaled-MFMA operand mapping (HW-verified
// rounds 1-7, absmax 0.0). A wave's fragment load is two fully coalesced
// global_load_dwordx4 (2 KB burst) -> no LDS, no barriers in the GEMM.
__device__ __forceinline__ i32x8 ld_gfrag(const uint8_t* p) {
  i32x4 lo = *(const i32x4*)p;
  i32x4 hi = *(const i32x4*)(p + 16);
  return __builtin_shufflevector(lo, hi, 0, 1, 2, 3, 4, 5, 6, 7);
}

// ---- fp32 -> fp8 e4m3 in fragment order, READ-COALESCED version ----
// One thread per 16 consecutive floats of one row (64 B contiguous read,
// sector-clean). Output: 16 fp8 bytes = one aligned 16 B store at
// (g*16+cb)*2048 + (h*32+rr)*32 + b0, b0 in {0,16}. (The old kernel
// gathered 16 B granules from 64 different 4KB-strided rows per
// instruction -> sector-scattered reads on the 206 MB weight matrix.)
// Pad rows (>= nrows_valid) are never written; caller pre-zeroes them.
__global__ __launch_bounds__(256)
void cvtq_frag16_kernel(const float* __restrict__ src, uint8_t* __restrict__ dst,
                        int nrows_valid, float scale) {
  int idx = blockIdx.x * 256 + threadIdx.x;     // one per 16 floats
  int total = nrows_valid * (DDIM / 16);
  if (idx >= total) return;
  int r  = idx >> 6;            // row (64 chunks of 16 per row)
  int c0 = (idx & 63) * 16;     // starting col
  const float4* s = (const float4*)(src + (size_t)r * DDIM + c0);
  uint32_t o[4];
  #pragma unroll
  for (int d = 0; d < 4; ++d) {
    float4 f = s[d];
    uint32_t v = 0;
    v = __builtin_amdgcn_cvt_pk_fp8_f32(f.x * scale, f.y * scale, v, false);
    v = __builtin_amdgcn_cvt_pk_fp8_f32(f.z * scale, f.w * scale, v, true);
    o[d] = v;
  }
  int g = r >> 5, rr = r & 31;
  int cb = c0 >> 6, h = (c0 >> 5) & 1, b0 = c0 & 31;
  size_t addr = (size_t)(g * 16 + cb) * 2048 + (size_t)((h * 32 + rr) * 32 + b0);
  *(uint4*)(dst + addr) = make_uint4(o[0], o[1], o[2], o[3]);
}

// ---- exact fp32 target logit: lt[n] = dot(x[n], w[target[n]]) ----
__global__ __launch_bounds__(256)
void tlogit_kernel(const float* __restrict__ x, const float* __restrict__ w,
                   const int* __restrict__ tgt, float* __restrict__ lt) {
  int n = blockIdx.x;
  int t = tgt[n];
  const float4* xr = (const float4*)(x + (size_t)n * DDIM);
  const float4* wr = (const float4*)(w + (size_t)t * DDIM);
  float4 a = xr[threadIdx.x];
  float4 b = wr[threadIdx.x];
  float s = a.x * b.x + a.y * b.y + a.z * b.z + a.w * b.w;
  #pragma unroll
  for (int m = 32; m; m >>= 1) s += __shfl_down(s, m);
  __shared__ float red[4];
  if ((threadIdx.x & 63) == 0) red[threadIdx.x >> 6] = s;
  __syncthreads();
  if (threadIdx.x == 0) lt[n] = red[0] + red[1] + red[2] + red[3];
}

// ---- fused fp8 GEMM (scaled 32x32x64 f8f6f4, unit scales) + exp + row-sum ----
// LDS-FREE (round-4 verbatim: best verified, 390 us). Block 256m x 128v, 4
// waves (2m x 2n), wave tile 128x64. Per k-iter each wave loads 6 operand
// fragments (4 A + 2 B, coalesced 2 KB bursts, L2-resident) and issues 8
// scaled MFMAs. No barriers; ~2.4 blocks/CU. Register budget proven: VGPR
// 84 arch + 128 acc, no spill. (128x128 wave tile spills at hipcc's
// allocator cap — closed path, rounds 5/7; dist-1 prefetch neutral, r6.)
// XCD swizzle: the 16 m-tiles of one v-slab share flat&7 -> one XCD streams
// each weight slab once; fragment A (4MB) L2-resident per XCD.
__global__ __launch_bounds__(256, 2)
void gemm_lse_kernel(const uint8_t* __restrict__ xqf,  // frag-ordered fp8 x
                     const uint8_t* __restrict__ wqf,  // frag-ordered fp8 w
                     float* __restrict__ S) {          // [NROWS] sum of exp
  const int tid  = threadIdx.x;
  const int wid  = tid >> 6;    // 0..3
  const int lane = tid & 63;
  const int c31  = lane & 31;
  const int h    = lane >> 5;   // 0..1

  // Block remap: grid (16,393) -> flat; same-v blocks share flat&7 (same XCD
  // under id%8 round-robin). Tail 16 blocks -> v-tile 392.
  const int flat = blockIdx.x + blockIdx.y * 16;
  int bm, vt;
  if (flat >= (NVT - 1) * 16) { vt = NVT - 1; bm = flat - (NVT - 1) * 16; }
  else { vt = (flat >> 7) * 8 + (flat & 7); bm = (flat >> 3) & 15; }
  const int m0 = bm * 256;
  const int v0 = vt * 128;

  const int wave_m = wid >> 1;  // 0..1
  const int wave_n = wid & 1;   // 0..1

  // Fragment base pointers: frag (g, c) at (g*16 + c)*2048 + lane*32.
  const uint8_t* pA[4];
  #pragma unroll
  for (int mi = 0; mi < 4; ++mi)
    pA[mi] = xqf + ((size_t)(bm * 8 + wave_m * 4 + mi) * 16) * 2048 + lane * 32;
  const uint8_t* pB[2];
  #pragma unroll
  for (int ni = 0; ni < 2; ++ni)
    pB[ni] = wqf + ((size_t)(vt * 4 + wave_n * 2 + ni) * 16) * 2048 + lane * 32;

  f32x16 acc[4][2] = {};

  #pragma unroll 1   // keep regs tame: no cross-iter pipelining
  for (int c = 0; c < 16; ++c) {
    const size_t co = (size_t)c * 2048;
    i32x8 bf0 = ld_gfrag(pB[0] + co);
    i32x8 bf1 = ld_gfrag(pB[1] + co);
    #pragma unroll
    for (int mi = 0; mi < 4; ++mi) {
      i32x8 afm = ld_gfrag(pA[mi] + co);
      acc[mi][0] = __builtin_amdgcn_mfma_scale_f32_32x32x64_f8f6f4(
          afm, bf0, acc[mi][0], 0, 0, 0, SCALE1, 0, SCALE1);
      acc[mi][1] = __builtin_amdgcn_mfma_scale_f32_32x32x64_f8f6f4(
          afm, bf1, acc[mi][1], 0, 0, 0, SCALE1, 0, SCALE1);
    }
  }

  // Epilogue: descale, exp, row-sum. 32x32 C/D: col = lane&31,
  // row = (reg&3) + 8*(reg>>2) + 4*(lane>>5).
  #pragma unroll
  for (int mi = 0; mi < 4; ++mi) {
    #pragma unroll
    for (int r = 0; r < 16; ++r) {
      float pacc = 0.f;
      #pragma unroll
      for (int ni = 0; ni < 2; ++ni) {
        int v = v0 + wave_n * 64 + ni * 32 + c31;
        float e = __expf(acc[mi][ni][r] * DESCALE);
        pacc += (v < VDIM) ? e : 0.f;   // mask vocab pad
      }
      pacc += __shfl_xor(pacc, 16);
      pacc += __shfl_xor(pacc, 8);
      pacc += __shfl_xor(pacc, 4);
      pacc += __shfl_xor(pacc, 2);
      pacc += __shfl_xor(pacc, 1);
      if (c31 == 0) {
        int row = m0 + wave_m * 128 + mi * 32 + (r & 3) + 8 * (r >> 2) + 4 * h;
        atomicAdd(&S[row], pacc);
      }
    }
  }
}

// ---- final: loss = mean(log(S[n]) - lt[n]) ----
__global__ __launch_bounds__(1024)
void loss_kernel(const float* __restrict__ S, const float* __restrict__ lt,
                 float* __restrict__ out) {
  float s = 0.f;
  for (int n = threadIdx.x; n < NROWS; n += 1024)
    s += logf(S[n]) - lt[n];
  #pragma unroll
  for (int m = 32; m; m >>= 1) s += __shfl_down(s, m);
  __shared__ float red[16];
  if ((threadIdx.x & 63) == 0) red[threadIdx.x >> 6] = s;
  __syncthreads();
  if (threadIdx.x == 0) {
    float t = 0.f;
    #pragma unroll
    for (int i = 0; i < 16; ++i) t += red[i];
    out[0] = t / (float)NROWS;
  }
}

extern "C" void kernel_launch(void* const* d_in, const int* in_sizes, int n_in,
                              void* d_out, int out_size, void* d_ws, size_t ws_size,
                              hipStream_t stream) {
  const float* x = (const float*)d_in[0];   // [4096,1024] fp32
  const float* w = (const float*)d_in[1];   // [50257,1024] fp32
  const int*   t = (const int*)d_in[2];     // [4096] int
  float* out = (float*)d_out;

  char* ws = (char*)d_ws;
  const size_t wq_bytes = (size_t)VPAD * DDIM;    // 51.5 MB fp8 (frag order)
  const size_t xq_bytes = (size_t)NROWS * DDIM;   //  4.2 MB fp8 (frag order)
  uint8_t* wqf = (uint8_t*)ws;
  uint8_t* xqf = (uint8_t*)(ws + wq_bytes);
  float*   S   = (float*)(ws + wq_bytes + xq_bytes);
  float*   lt  = S + NROWS;

  if (ws_size < wq_bytes + xq_bytes + 2 * NROWS * sizeof(float)) return;

  hipMemsetAsync(S, 0, NROWS * sizeof(float), stream);
  // Zero the pad tail of wqf: g-groups 1570..1571 (rows 50240..50303)
  // contain all pad rows (>= VDIM) interleaved; cvtq only writes valid rows.
  {
    const size_t tail_off = (size_t)1570 * 16 * 2048;   // 51,445,760
    hipMemsetAsync(wqf + tail_off, 0, wq_bytes - tail_off, stream);
  }
  {
    int total_w = VDIM * (DDIM / 16);
    cvtq_frag16_kernel<<<(total_w + 255) / 256, 256, 0, stream>>>(
        w, wqf, VDIM, 64.0f);
    int total_x = NROWS * (DDIM / 16);
    cvtq_frag16_kernel<<<(total_x + 255) / 256, 256, 0, stream>>>(
        x, xqf, NROWS, 8.0f);
  }
  tlogit_kernel<<<NROWS, 256, 0, stream>>>(x, w, t, lt);

  dim3 grid(NMT, NVT);  // (16, 393)
  gemm_lse_kernel<<<grid, 256, 0, stream>>>(xqf, wqf, S);

  loss_kernel<<<1, 1024, 0, stream>>>(S, lt, out);
}